// Round 14
// baseline (484.400 us; speedup 1.0000x reference)
//
#include <hip/hip_runtime.h>
#include <hip/hip_bf16.h>
#include <math.h>

// SSMBlock: B=8, T=2048, C=1024, NF=64. R = 16384 rows.
// Round 18: small-shift step PAIRS (1,2),(4,8),(16,32) fused via halo
// recompute in scan_pair: 112-row f32 G-state in LDS (rows r0-48..r0+63),
// step A computes state rows 16..111 (96 rows, z2 as 64+32-row passes with
// acc[4][4] reuse -> no spill), step B rows 48..111, emit 64 rows. No grid
// barrier (reads only prev-dispatch Gsrc / intra-block LDS). 11 -> 8 scan
// dispatches. Singles n=64..1024 unchanged (round-13 body + XCD row map).
// ws: Xb 32M | (Wqb 2M, Wob 256K) | Vb 32M | aWt+Mt 2.25M | pWt 2M
//     | w2t 256K | w1f 256K | Ga/Gb 16M | fid | c1 | bg | W21t 32K

#define R_ROWS 16384
#define T_DIM  2048
#define C_DIM  1024
#define SROWS  112
#define GP     132

typedef unsigned short u16;
typedef __attribute__((ext_vector_type(8))) short short8;
typedef __attribute__((ext_vector_type(4))) float f32x4;

__device__ __forceinline__ u16 f2bf(float f) {
  union { float f; unsigned u; } v; v.f = f;
  unsigned r = v.u + 0x7fffu + ((v.u >> 16) & 1u);
  return (u16)(r >> 16);
}
__device__ __forceinline__ float bf2f(u16 h) {
  union { unsigned u; float f; } v; v.u = ((unsigned)h) << 16;
  return v.f;
}
__device__ __forceinline__ void gld16(const void* g, void* l) {
  __builtin_amdgcn_global_load_lds(
      (const __attribute__((address_space(1))) void*)g,
      (__attribute__((address_space(3))) void*)l, 16, 0, 0);
}

// ---------------- elementwise ----------------------------------------------
__global__ __launch_bounds__(256) void cvt_bf16(const float* __restrict__ in,
                                                u16* __restrict__ out, int n8) {
  const int i = blockIdx.x * 256 + threadIdx.x;
  if (i >= n8) return;
  const float4 a = ((const float4*)in)[2 * i];
  const float4 b = ((const float4*)in)[2 * i + 1];
  alignas(16) u16 t[8] = {f2bf(a.x), f2bf(a.y), f2bf(a.z), f2bf(a.w),
                          f2bf(b.x), f2bf(b.y), f2bf(b.z), f2bf(b.w)};
  ((uint4*)out)[i] = *(const uint4*)t;
}

// ---------------- prep megakernel 1: weight conversions ---------------------
__device__ __forceinline__ void cvtT_tile(const float* W, u16* Wt, int K, int N,
                                          int noff, int k0, int n0,
                                          float (*t)[33]) {
  const int tx = threadIdx.x & 31, ty = threadIdx.x >> 5;
#pragma unroll
  for (int i = 0; i < 32; i += 8)
    t[ty + i][tx] = W[(size_t)(k0 + ty + i) * N + noff + n0 + tx];
  __syncthreads();
#pragma unroll
  for (int i = 0; i < 32; i += 8)
    Wt[(size_t)(n0 + ty + i) * K + k0 + tx] = f2bf(t[tx][ty + i]);
}

__global__ __launch_bounds__(256) void prep_weights(
    const float* __restrict__ attn_W, const float* __restrict__ proj_W,
    const float* __restrict__ out_W, const float* __restrict__ freq_W,
    u16* __restrict__ aWt, u16* __restrict__ pWt, u16* __restrict__ w2t,
    u16* __restrict__ w1f, u16* __restrict__ Wqb, u16* __restrict__ Wob) {
  __shared__ float t[32][33];
  const int bid = blockIdx.x;
  if (bid < 1024) {
    cvtT_tile(attn_W, aWt, 1024, 2048, 1024, (bid & 31) * 32, (bid >> 5) * 32, t);
  } else if (bid < 2048) {
    const int b = bid - 1024;
    cvtT_tile(proj_W, pWt, 1024, 1024, 0, (b & 31) * 32, (b >> 5) * 32, t);
  } else if (bid < 2176) {
    const int b = bid - 2048;
    cvtT_tile(out_W, w2t, 128, 1024, 0, (b & 3) * 32, (b >> 2) * 32, t);
  } else if (bid < 2304) {
    const int b = bid - 2176;
    const int k0 = (b & 63) * 32, n0 = (b >> 6) * 32;
    const int tx = threadIdx.x & 31, ty = threadIdx.x >> 5;
#pragma unroll
    for (int i = 0; i < 32; i += 8)
      t[ty + i][tx] = freq_W[(size_t)(k0 + ty + i) * 64 + n0 + tx];
    __syncthreads();
#pragma unroll
    for (int i = 0; i < 32; i += 8) {
      const int k = k0 + tx;
      const int row = (n0 + ty + i) + ((k >= 1024) ? 64 : 0);
      w1f[(size_t)row * 1024 + (k & 1023)] = f2bf(t[tx][ty + i]);
    }
  } else if (bid < 3328) {
    const int c = bid - 2304, k0 = threadIdx.x * 4;
    const float4 a = *(const float4*)&attn_W[(size_t)c * 2048 + k0];
    alignas(8) u16 tt[4] = {f2bf(a.x), f2bf(a.y), f2bf(a.z), f2bf(a.w)};
    *(uint2*)&Wqb[(size_t)c * 1024 + k0] = *(const uint2*)tt;
  } else {
    const int c = bid - 3328, k0 = threadIdx.x * 4;
    const float4 a = *(const float4*)&out_W[(size_t)c * 1024 + k0];
    alignas(8) u16 tt[4] = {f2bf(a.x), f2bf(a.y), f2bf(a.z), f2bf(a.w)};
    *(uint2*)&Wob[(size_t)c * 1024 + k0] = *(const uint2*)tt;
  }
}

// ---------------- prep megakernel 2: small derived tensors ------------------
__device__ __forceinline__ void gm_body(const u16* w1f, const u16* B,
                                        u16* Mt, int ldO, int n0, u16* As) {
  const int tid = threadIdx.x, lane = tid & 63, w = tid >> 6;
  const int ln = lane & 15, qd = lane >> 4;
  const int wm = w & 1, wn = w >> 1;
  const int srow = w * 32 + (lane >> 3);
  const int scol = ((lane & 7) ^ ((lane >> 3) & 7)) * 8;
  f32x4 acc[4][2] = {};
  for (int kt = 0; kt < 1024; kt += 64) {
    __syncthreads();
#pragma unroll
    for (int j = 0; j < 4; j++)
      gld16(&w1f[(size_t)(srow + j * 8) * 1024 + kt + scol],
            &As[(w * 32 + j * 8) * 64]);
    __syncthreads();
#pragma unroll
    for (int ks = 0; ks < 2; ks++) {
      short8 af[4];
#pragma unroll
      for (int i = 0; i < 4; i++) {
        const int ar = wm * 64 + i * 16 + ln;
        af[i] = *(const short8*)&As[ar * 64 + ((ks * 4 + qd) ^ (ar & 7)) * 8];
      }
#pragma unroll
      for (int nt = 0; nt < 2; nt++) {
        const short8 b = *(const short8*)&B[(size_t)(n0 + wn * 32 + nt * 16 + ln) * 1024 +
                                            kt + ks * 32 + qd * 8];
#pragma unroll
        for (int i = 0; i < 4; i++)
          acc[i][nt] = __builtin_amdgcn_mfma_f32_16x16x32_bf16(af[i], b, acc[i][nt], 0, 0, 0);
      }
    }
  }
#pragma unroll
  for (int i = 0; i < 4; i++)
#pragma unroll
    for (int nt = 0; nt < 2; nt++)
#pragma unroll
      for (int r = 0; r < 4; r++)
        Mt[(size_t)(wm * 64 + i * 16 + qd * 4 + r) * ldO +
           n0 + wn * 32 + nt * 16 + ln] = f2bf(acc[i][nt][r]);
}

__device__ __forceinline__ void dotred_body(const float* ab, const u16* w1f,
                                            float* outv, float* red) {
  const int tid = threadIdx.x, j = tid >> 1, part = tid & 1;
  float s = 0.f;
  for (int k = part * 512; k < part * 512 + 512; k++)
    s += ab[k] * bf2f(w1f[(size_t)j * 1024 + k]);
  red[tid] = s;
  __syncthreads();
  if (part == 0) outv[j] = red[2 * j] + red[2 * j + 1];
}

__global__ __launch_bounds__(256) void prep_small(
    const float* __restrict__ ident, const float* __restrict__ freq_W,
    const float* __restrict__ attn_b, const float* __restrict__ out_b,
    const u16* __restrict__ w1f, const u16* __restrict__ Wqb,
    const u16* __restrict__ Wob, float* __restrict__ fid,
    float* __restrict__ bgv, float* __restrict__ c1,
    u16* __restrict__ Mt, u16* __restrict__ W21t) {
  __shared__ u16 sh[8192];  // 16KB: gm As / reduction buffer
  float* red = (float*)sh;
  const int bid = blockIdx.x;
  if (bid == 0) {
    const int tid = threadIdx.x;
    const int j = tid >> 2, part = tid & 3;
    float s = 0.f;
    for (int k = part * 256; k < part * 256 + 256; k++)
      s += ident[k] * freq_W[(size_t)k * 64 + j];
    red[tid] = s;
    __syncthreads();
    if (part == 0) fid[j] = red[tid] + red[tid + 1] + red[tid + 2] + red[tid + 3];
  } else if (bid == 1) {
    dotred_body(attn_b, w1f, bgv, red);
  } else if (bid == 2) {
    dotred_body(out_b, w1f, c1, red);
  } else if (bid < 19) {
    gm_body(w1f, Wqb, Mt, 1024, (bid - 3) * 64, sh);
  } else {
    gm_body(w1f, Wob, W21t, 128, (bid - 19) * 64, sh);
  }
}

// ---------------- big GEMMs (m97-style + XCD swizzle) -----------------------
#define GEMM_KLOOP(Aptr, Bptr)                                                 \
  const int tid = threadIdx.x, lane = tid & 63, w = tid >> 6;                  \
  const int ln = lane & 15, qd = lane >> 4;                                    \
  const int wm = w & 1, wn = w >> 1;                                           \
  const int nbx = gridDim.x;                                                   \
  const int bid0 = blockIdx.y * nbx + blockIdx.x;                              \
  const int nwg = nbx * gridDim.y;                                             \
  const int bid = (bid0 & 7) * (nwg >> 3) + (bid0 >> 3);                       \
  const int n0 = (bid % nbx) * 128, m0 = (bid / nbx) * 128;                    \
  const int srow = w * 32 + (lane >> 3);                                       \
  const int sl = (lane & 7) ^ ((lane >> 3) & 7);                               \
  const int scol = sl * 8;                                                     \
  f32x4 acc[4][4] = {};                                                        \
  for (int kt = 0; kt < 1024; kt += 64) {                                      \
    __syncthreads();                                                           \
    _Pragma("unroll") for (int j = 0; j < 4; j++) {                            \
      gld16(&Aptr[(size_t)(m0 + srow + j * 8) * 1024 + kt + scol],             \
            &As[(w * 32 + j * 8) * 64]);                                       \
      gld16(&Bptr[(size_t)(n0 + srow + j * 8) * 1024 + kt + scol],             \
            &Bs[(w * 32 + j * 8) * 64]);                                       \
    }                                                                          \
    __syncthreads();                                                           \
    _Pragma("unroll") for (int ks = 0; ks < 2; ks++) {                         \
      short8 af[4], bf_[4];                                                    \
      _Pragma("unroll") for (int i = 0; i < 4; i++) {                          \
        const int ar = wm * 64 + i * 16 + ln;                                  \
        af[i] = *(const short8*)&As[ar * 64 + ((ks * 4 + qd) ^ (ar & 7)) * 8]; \
      }                                                                        \
      _Pragma("unroll") for (int j = 0; j < 4; j++) {                          \
        const int br = wn * 64 + j * 16 + ln;                                  \
        bf_[j] = *(const short8*)&Bs[br * 64 + ((ks * 4 + qd) ^ (br & 7)) * 8];\
      }                                                                        \
      _Pragma("unroll") for (int i = 0; i < 4; i++)                            \
      _Pragma("unroll") for (int j = 0; j < 4; j++)                            \
        acc[i][j] = __builtin_amdgcn_mfma_f32_16x16x32_bf16(af[i], bf_[j],     \
                                                            acc[i][j], 0, 0, 0);\
    }                                                                          \
  }                                                                            \
  __syncthreads();

// V = x @ attn_Wv + b_v (n0 < 1024)  |  G0 = x @ Mt^T + bg (n0 == 1024).
__global__ __launch_bounds__(256) void gemm_vg_mfma(
    const u16* __restrict__ A, const u16* __restrict__ Bt,
    const float* __restrict__ bias, const float* __restrict__ bg,
    u16* __restrict__ Vb, float* __restrict__ G) {
  __shared__ u16 S[16384];
  u16* As = S;
  u16* Bs = S + 8192;
  GEMM_KLOOP(A, Bt)
  if (n0 < 1024) {
#pragma unroll
    for (int j = 0; j < 4; j++) {
      const int col = wn * 64 + j * 16 + ln;
      const float bv = bias[n0 + col];
#pragma unroll
      for (int i = 0; i < 4; i++)
#pragma unroll
        for (int r = 0; r < 4; r++)
          S[(wm * 64 + i * 16 + qd * 4 + r) * 128 + col] = f2bf(acc[i][j][r] + bv);
    }
    __syncthreads();
#pragma unroll
    for (int it = 0; it < 8; it++) {
      const int idx = it * 256 + tid;
      const int row = idx >> 4, seg = idx & 15;
      *(uint4*)&Vb[(size_t)(m0 + row) * 1024 + n0 + seg * 8] = ((const uint4*)S)[idx];
    }
  } else {  // G0 block: direct f32 write, bias bg
#pragma unroll
    for (int j = 0; j < 4; j++) {
      const int col = wn * 64 + j * 16 + ln;
      const float bv = bg[col];
#pragma unroll
      for (int i = 0; i < 4; i++)
#pragma unroll
        for (int r = 0; r < 4; r++)
          G[(size_t)(m0 + wm * 64 + i * 16 + qd * 4 + r) * 128 + col] =
              acc[i][j][r] + bv;
    }
  }
}

__global__ __launch_bounds__(256) void gemm_proj_mfma(
    const u16* __restrict__ A, const u16* __restrict__ Bt,
    const float* __restrict__ bias, float* __restrict__ OUT) {
  __shared__ u16 S[16384];
  u16* As = S;
  u16* Bs = S + 8192;
  GEMM_KLOOP(A, Bt)
  float* Csf = (float*)S;
#pragma unroll
  for (int p = 0; p < 2; p++) {
    if (wm == p) {
#pragma unroll
      for (int j = 0; j < 4; j++) {
        const int col = wn * 64 + j * 16 + ln;
        const float bv = bias[n0 + col];
#pragma unroll
        for (int i = 0; i < 4; i++)
#pragma unroll
          for (int r = 0; r < 4; r++)
            Csf[(i * 16 + qd * 4 + r) * 128 + col] = acc[i][j][r] + bv;
      }
    }
    __syncthreads();
#pragma unroll
    for (int it = 0; it < 8; it++) {
      const int idx = it * 256 + tid;
      const int row = idx >> 5, seg = idx & 31;
      *(uint4*)&OUT[(size_t)(m0 + p * 64 + row) * 1024 + n0 + seg * 4] =
          ((const uint4*)Csf)[idx];
    }
    __syncthreads();
  }
}

// ---------------- scan helpers ----------------------------------------------
// z2 rowmax pass over NT row-tiles starting at state row rb (swapped operands).
template <int NT>
__device__ __forceinline__ void zpass(const u16* S, const u16* w2b,
                                      const float* b2, unsigned* rmax,
                                      int rb, int wv, int ln, int qd, int lane) {
  f32x4 acc[NT][4] = {};
#pragma unroll
  for (int ks = 0; ks < 4; ks++) {
    short8 b[4];
#pragma unroll
    for (int nt = 0; nt < 4; nt++)
      b[nt] = *(const short8*)&w2b[(size_t)(nt * 16 + ln) * 128 + ks * 32 + qd * 8];
    short8 af[NT];
#pragma unroll
    for (int i = 0; i < NT; i++) {
      const int ar = rb + i * 16 + ln;
      const int u = ks * 4 + qd;
      af[i] = *(const short8*)&S[ar * 128 + ((u & 8) | ((u ^ ar) & 7)) * 8];
    }
#pragma unroll
    for (int nt = 0; nt < 4; nt++)
#pragma unroll
      for (int i = 0; i < NT; i++)
        acc[i][nt] = __builtin_amdgcn_mfma_f32_16x16x32_bf16(b[nt], af[i], acc[i][nt], 0, 0, 0);
  }
  float mx[NT];
#pragma unroll
  for (int i = 0; i < NT; i++) mx[i] = 0.f;
#pragma unroll
  for (int nt = 0; nt < 4; nt++) {
    const float4 bb = *(const float4*)&b2[wv * 64 + nt * 16 + qd * 4];
    const float br4[4] = {bb.x, bb.y, bb.z, bb.w};
#pragma unroll
    for (int i = 0; i < NT; i++)
#pragma unroll
      for (int r = 0; r < 4; r++)
        mx[i] = fmaxf(mx[i], fabsf(acc[i][nt][r] + br4[r]));
  }
#pragma unroll
  for (int i = 0; i < NT; i++) {
    float v = mx[i];
    v = fmaxf(v, __shfl_xor(v, 16, 64));
    v = fmaxf(v, __shfl_xor(v, 32, 64));
    if (lane < 16) atomicMax(&rmax[rb + i * 16 + lane], __float_as_uint(v));
  }
}

// G' = (S @ W21t^T + c1) * inv over 64 rows at rb -> GS (16 waves: 4x4 tiles)
__device__ __forceinline__ void gpass4(const u16* S, const u16* W21t,
                                       const float* c1, const unsigned* rmax,
                                       float* GS, int rb, int wv, int ln, int qd) {
  const int wm = wv & 3, wn = wv >> 2;
  f32x4 g[2] = {};
#pragma unroll
  for (int ks = 0; ks < 4; ks++) {
    const int ar = rb + wm * 16 + ln;
    const int u = ks * 4 + qd;
    const short8 a = *(const short8*)&S[ar * 128 + ((u & 8) | ((u ^ ar) & 7)) * 8];
#pragma unroll
    for (int c = 0; c < 2; c++) {
      const short8 b = *(const short8*)&W21t[(size_t)(wn * 32 + c * 16 + ln) * 128 +
                                             ks * 32 + qd * 8];
      g[c] = __builtin_amdgcn_mfma_f32_16x16x32_bf16(a, b, g[c], 0, 0, 0);
    }
  }
#pragma unroll
  for (int c = 0; c < 2; c++) {
    const int col = wn * 32 + c * 16 + ln;
    const float cb = c1[col];
#pragma unroll
    for (int r = 0; r < 4; r++) {
      const int row = rb + wm * 16 + qd * 4 + r;
      const float invr = 1.0f / (__uint_as_float(rmax[row]) + 1e-6f);
      GS[row * GP + col] = (g[c][r] + cb) * invr;
    }
  }
}

// G' over 32 rows at rb -> GS (16 waves: 2 row-tiles x 8 col-groups)
__device__ __forceinline__ void gpass2(const u16* S, const u16* W21t,
                                       const float* c1, const unsigned* rmax,
                                       float* GS, int rb, int wv, int ln, int qd) {
  const int wm = wv & 1, wn = wv >> 1;
  f32x4 g = {};
#pragma unroll
  for (int ks = 0; ks < 4; ks++) {
    const int ar = rb + wm * 16 + ln;
    const int u = ks * 4 + qd;
    const short8 a = *(const short8*)&S[ar * 128 + ((u & 8) | ((u ^ ar) & 7)) * 8];
    const short8 b = *(const short8*)&W21t[(size_t)(wn * 16 + ln) * 128 +
                                           ks * 32 + qd * 8];
    g = __builtin_amdgcn_mfma_f32_16x16x32_bf16(a, b, g, 0, 0, 0);
  }
  const int col = wn * 16 + ln;
  const float cb = c1[col];
#pragma unroll
  for (int r = 0; r < 4; r++) {
    const int row = rb + wm * 16 + qd * 4 + r;
    const float invr = 1.0f / (__uint_as_float(rmax[row]) + 1e-6f);
    GS[row * GP + col] = (g[r] + cb) * invr;
  }
}

// ---------------- fused step-PAIR scan (nA, 2nA), nA in {1,4,16} -------------
// 1024 threads (16 waves), 64 output rows/block, grid 256, XCD row map.
// 112-row f32 G-state in LDS (state row sr <-> global row r0-48+sr).
// Step A: S+z2+G' on state rows 16..111 ; step B: rows 48..111 ; emit 48..111.
__global__ __launch_bounds__(1024, 4) void scan_pair(
    const float* __restrict__ Gsrc, float* __restrict__ Gdst,
    const u16* __restrict__ W21t, const u16* __restrict__ W2t,
    const float* __restrict__ b1, const float* __restrict__ b2,
    const float* __restrict__ fid, const float* __restrict__ c1, int nA) {
  __shared__ float GS[SROWS * GP];   // 59136 B
  __shared__ u16 S[SROWS * 128];     // 28672 B
  __shared__ unsigned rmax[SROWS];
  const int tid = threadIdx.x, lane = tid & 63, wv = tid >> 6;
  const int ln = lane & 15, qd = lane >> 4;
  const int bid = blockIdx.x;
  const int r0 = (((bid & 7) << 5) + (bid >> 3)) * 64;
  // init: G state rows [r0-48, r0+64)
#pragma unroll
  for (int it = 0; it < 4; it++) {
    const int idx = it * 1024 + tid;            // 3584 float4
    if (idx < SROWS * 32) {
      const int row = idx >> 5, c4 = (idx & 31) << 2;
      const int g = r0 - 48 + row;
      float4 v = {0.f, 0.f, 0.f, 0.f};
      if (g >= 0) v = *(const float4*)&Gsrc[(size_t)g * 128 + c4];
      *(float4*)&GS[row * GP + c4] = v;
    }
  }
  const u16* w2b = W2t + (size_t)wv * 64 * 128;
  int n = nA;
  for (int s = 0; s < 2; s++, n <<= 1) {
    const int srBeg = s ? 48 : 16;
    __syncthreads();  // GS stable (init or prior G'); rmax reads done
    if (tid < SROWS) rmax[tid] = 0u;
    // ---- P0: f = G1|fid + G2 + b1 ; sincos -> S rows [srBeg, 112)
    {
      const int sr = srBeg + (tid >> 3);
      if (sr < SROWS) {
        const int js = (tid & 7) << 3;
        const int g = r0 - 48 + sr, tl = g & (T_DIM - 1);
        float g1v[8];
        if (tl >= n) {
          const float* p = &GS[(sr - n) * GP + js];
          const float4 a0 = *(const float4*)p;
          const float4 a1 = *(const float4*)(p + 4);
          g1v[0] = a0.x; g1v[1] = a0.y; g1v[2] = a0.z; g1v[3] = a0.w;
          g1v[4] = a1.x; g1v[5] = a1.y; g1v[6] = a1.z; g1v[7] = a1.w;
        } else {
          const float4 a0 = *(const float4*)&fid[js];
          const float4 a1 = *(const float4*)&fid[js + 4];
          g1v[0] = a0.x; g1v[1] = a0.y; g1v[2] = a0.z; g1v[3] = a0.w;
          g1v[4] = a1.x; g1v[5] = a1.y; g1v[6] = a1.z; g1v[7] = a1.w;
        }
        const float4 g2a = *(const float4*)&GS[sr * GP + 64 + js];
        const float4 g2b = *(const float4*)&GS[sr * GP + 64 + js + 4];
        const float4 ba = *(const float4*)&b1[js];
        const float4 bb4 = *(const float4*)&b1[js + 4];
        float f[8] = {g1v[0] + g2a.x + ba.x,  g1v[1] + g2a.y + ba.y,
                      g1v[2] + g2a.z + ba.z,  g1v[3] + g2a.w + ba.w,
                      g1v[4] + g2b.x + bb4.x, g1v[5] + g2b.y + bb4.y,
                      g1v[6] + g2b.z + bb4.z, g1v[7] + g2b.w + bb4.w};
        alignas(16) u16 sn[8], cs[8];
#pragma unroll
        for (int c = 0; c < 8; c++) {
          float sv, cv;
          __sincosf(f[c], &sv, &cv);
          sn[c] = f2bf(sv);
          cs[c] = f2bf(cv);
        }
        const int ps = ((js >> 3) ^ (sr & 7)) & 7;
        *(uint4*)&S[sr * 128 + ps * 8] = *(const uint4*)sn;
        *(uint4*)&S[sr * 128 + (8 | ps) * 8] = *(const uint4*)cs;
      }
    }
    __syncthreads();  // S ready; all GS reads of this step retired
    // ---- P1: z2 rowmax (sequential passes, acc reuse)
    if (s == 0) {
      zpass<4>(S, w2b, b2, rmax, 16, wv, ln, qd, lane);
      zpass<2>(S, w2b, b2, rmax, 80, wv, ln, qd, lane);
    } else {
      zpass<4>(S, w2b, b2, rmax, 48, wv, ln, qd, lane);
    }
    __syncthreads();  // rmax ready
    // ---- G' -> GS (in place; this step's GS reads all retired at S barrier)
    if (s == 0) {
      gpass4(S, W21t, c1, rmax, GS, 16, wv, ln, qd);
      gpass2(S, W21t, c1, rmax, GS, 80, wv, ln, qd);
    } else {
      gpass4(S, W21t, c1, rmax, GS, 48, wv, ln, qd);
    }
  }
  __syncthreads();
  // emit state rows 48..111 -> Gdst rows [r0, r0+64)
#pragma unroll
  for (int it = 0; it < 2; it++) {
    const int idx = it * 1024 + tid;            // 2048 float4
    const int row = idx >> 5, c4 = (idx & 31) << 2;
    *(float4*)&Gdst[(size_t)(r0 + row) * 128 + c4] =
        *(const float4*)&GS[(48 + row) * GP + c4];
  }
}

// ---------------- fused scan step (round-13 body + XCD row map) --------------
// 1024 threads (16 waves), 64 rows/block, grid 256.
// flags: 1 = last step: write Y = q*v into Yout ; 2 = compute Gdst.
__global__ __launch_bounds__(1024, 4) void scan_fused(
    const float* __restrict__ Gsrc, float* __restrict__ Gdst,
    const u16* __restrict__ W21t, const u16* __restrict__ W2t,
    const float* __restrict__ b1, const float* __restrict__ b2,
    const float* __restrict__ fid, const float* __restrict__ c1,
    const u16* __restrict__ Vb, u16* __restrict__ Yout, int n, int flags) {
  __shared__ u16 S[64 * 128];  // 16KB
  __shared__ unsigned rmax[64];
  const int tid = threadIdx.x, lane = tid & 63, wv = tid >> 6;
  const int ln = lane & 15, qd = lane >> 4;
  const int bid = blockIdx.x;
  const int r0 = (((bid & 7) << 5) + (bid >> 3)) * 64;
  if (tid < 64) rmax[tid] = 0u;
  // ---- P0
  {
    const int r = tid >> 4, js = (tid & 15) << 2;
    const int gr = r0 + r, tl = gr & (T_DIM - 1);
    const float* g1p = (tl >= n) ? &Gsrc[(size_t)(gr - n) * 128 + js] : &fid[js];
    const float4 g1 = *(const float4*)g1p;
    const float4 g2 = *(const float4*)&Gsrc[(size_t)gr * 128 + 64 + js];
    const float4 bb = *(const float4*)&b1[js];
    float f[4] = {g1.x + g2.x + bb.x, g1.y + g2.y + bb.y,
                  g1.z + g2.z + bb.z, g1.w + g2.w + bb.w};
    alignas(8) u16 sn[4], cs[4];
#pragma unroll
    for (int c = 0; c < 4; c++) {
      float sv, cv;
      __sincosf(f[c], &sv, &cv);
      sn[c] = f2bf(sv);
      cs[c] = f2bf(cv);
    }
    const int u = js >> 3, half = (js >> 2) & 1, rx = r & 7;
    const int ps = (u ^ rx) & 7;
    const int pc = 8 | ps;
    *(uint2*)&S[r * 128 + ps * 8 + half * 4] = *(const uint2*)sn;
    *(uint2*)&S[r * 128 + pc * 8 + half * 4] = *(const uint2*)cs;
  }
  __syncthreads();
  // ---- P1: z2^T; wave owns 64 cols
  const u16* w2b = W2t + (size_t)wv * 64 * 128;
  f32x4 acc[4][4] = {};
#pragma unroll
  for (int ks = 0; ks < 4; ks++) {
    short8 af[4];
#pragma unroll
    for (int i = 0; i < 4; i++) {
      const int ar = i * 16 + ln;
      const int u = ks * 4 + qd;
      af[i] = *(const short8*)&S[ar * 128 + ((u & 8) | ((u ^ ar) & 7)) * 8];
    }
#pragma unroll
    for (int nt = 0; nt < 4; nt++) {
      const short8 b = *(const short8*)&w2b[(size_t)(nt * 16 + ln) * 128 + ks * 32 + qd * 8];
#pragma unroll
      for (int i = 0; i < 4; i++)
        acc[i][nt] = __builtin_amdgcn_mfma_f32_16x16x32_bf16(b, af[i], acc[i][nt], 0, 0, 0);
    }
  }
  float mx[4] = {0.f, 0.f, 0.f, 0.f};
#pragma unroll
  for (int nt = 0; nt < 4; nt++) {
    const float4 bb = *(const float4*)&b2[wv * 64 + nt * 16 + qd * 4];
    const float br4[4] = {bb.x, bb.y, bb.z, bb.w};
#pragma unroll
    for (int i = 0; i < 4; i++)
#pragma unroll
      for (int r = 0; r < 4; r++) {
        const float v = acc[i][nt][r] + br4[r];
        acc[i][nt][r] = v;
        mx[i] = fmaxf(mx[i], fabsf(v));
      }
  }
#pragma unroll
  for (int i = 0; i < 4; i++) {
    float v = mx[i];
    v = fmaxf(v, __shfl_xor(v, 16, 64));
    v = fmaxf(v, __shfl_xor(v, 32, 64));
    if (lane < 16) atomicMax(&rmax[i * 16 + lane], __float_as_uint(v));
  }
  __syncthreads();
  if (flags & 1) {  // last step: Y = (z2*inv) * v
    float inv[4];
#pragma unroll
    for (int i = 0; i < 4; i++)
      inv[i] = 1.0f / (__uint_as_float(rmax[i * 16 + ln]) + 1e-6f);
#pragma unroll
    for (int i = 0; i < 4; i++) {
      const int row = i * 16 + ln;
#pragma unroll
      for (int nt = 0; nt < 4; nt++) {
        const int col = wv * 64 + nt * 16 + qd * 4;
        const uint2 vv = *(const uint2*)&Vb[(size_t)(r0 + row) * 1024 + col];
        const u16* vp = (const u16*)&vv;
        uint2 pv;
        pv.x = (unsigned)f2bf(acc[i][nt][0] * inv[i] * bf2f(vp[0])) |
               ((unsigned)f2bf(acc[i][nt][1] * inv[i] * bf2f(vp[1])) << 16);
        pv.y = (unsigned)f2bf(acc[i][nt][2] * inv[i] * bf2f(vp[2])) |
               ((unsigned)f2bf(acc[i][nt][3] * inv[i] * bf2f(vp[3])) << 16);
        *(uint2*)&Yout[(size_t)(r0 + row) * 1024 + col] = pv;
      }
    }
  }
  if (flags & 2) {  // G' = (S @ W21t^T + c1) * inv : 64x128 out, K=128
    const int wm3 = wv & 3, wn3 = wv >> 2;
    f32x4 g[2] = {};
#pragma unroll
    for (int ks = 0; ks < 4; ks++) {
      const int ar = wm3 * 16 + ln;
      const int u = ks * 4 + qd;
      const short8 a = *(const short8*)&S[ar * 128 + ((u & 8) | ((u ^ ar) & 7)) * 8];
#pragma unroll
      for (int c = 0; c < 2; c++) {
        const short8 b = *(const short8*)&W21t[(size_t)(wn3 * 32 + c * 16 + ln) * 128 +
                                               ks * 32 + qd * 8];
        g[c] = __builtin_amdgcn_mfma_f32_16x16x32_bf16(a, b, g[c], 0, 0, 0);
      }
    }
#pragma unroll
    for (int c = 0; c < 2; c++) {
      const int col = wn3 * 32 + c * 16 + ln;
      const float cb = c1[col];
#pragma unroll
      for (int r = 0; r < 4; r++) {
        const int row = wm3 * 16 + qd * 4 + r;
        const float invr = 1.0f / (__uint_as_float(rmax[row]) + 1e-6f);
        Gdst[(size_t)(r0 + row) * 128 + col] = (g[c][r] + cb) * invr;
      }
    }
  }
}

// ---------------- launch ----------------------------------------------------
extern "C" void kernel_launch(void* const* d_in, const int* in_sizes, int n_in,
                              void* d_out, int out_size, void* d_ws, size_t ws_size,
                              hipStream_t stream) {
  const float* x      = (const float*)d_in[0];
  const float* attn_W = (const float*)d_in[1];
  const float* attn_b = (const float*)d_in[2];
  const float* freq_W = (const float*)d_in[3];
  const float* freq_b = (const float*)d_in[4];
  const float* out_W  = (const float*)d_in[5];
  const float* out_b  = (const float*)d_in[6];
  const float* proj_W = (const float*)d_in[7];
  const float* proj_b = (const float*)d_in[8];
  const float* ident  = (const float*)d_in[9];
  float* out = (float*)d_out;

  const size_t RC = (size_t)R_ROWS * C_DIM;
  u16* Xb  = (u16*)d_ws;                     // 32MB (x bf16, later Y)
  u16* Qb  = Xb + RC;                        // 32MB region, repurposed:
  u16* Wqb = Qb;                             //   attn_Wq bf16 [1024][1024] 2MB
  u16* Wob = Qb + (size_t)1024 * 1024;       //   out_W bf16 [128][1024] 256KB
  u16* Vb  = Qb + RC;                        // 32MB
  u16* aWt = Vb + RC;                        // B = [aWt 1024 rows | Mt 128 rows]
  u16* Mt  = aWt + (size_t)1024 * 1024;      //   (2.25MB of the 4MB region)
  u16* pWt = aWt + (size_t)2048 * 1024;      // 2MB
  u16* w2t = pWt + (size_t)1024 * 1024;      // 256KB
  u16* w1f = w2t + (size_t)1024 * 128;       // 256KB
  float* Ga  = (float*)(w1f + (size_t)128 * 1024);  // 8MB
  float* Gb  = Ga + (size_t)R_ROWS * 128;           // 8MB
  float* fid = Gb + (size_t)R_ROWS * 128;           // 256B
  float* c1  = fid + 64;                            // 512B
  float* bgv = c1 + 128;                            // 512B
  u16* W21t  = (u16*)(bgv + 128);                   // 32KB

  // prep (3 dispatches)
  cvt_bf16<<<8192, 256, 0, stream>>>(x, Xb, (int)(RC / 8));
  prep_weights<<<3456, 256, 0, stream>>>(attn_W, proj_W, out_W, freq_W,
                                         aWt, pWt, w2t, w1f, Wqb, Wob);
  prep_small<<<21, 256, 0, stream>>>(ident, freq_W, attn_b, out_b, w1f, Wqb,
                                     Wob, fid, bgv, c1, Mt, W21t);

  // V = x @ attn_Wv + b_v  AND  G0 = x @ Mt^T + bg (fused, grid 9x128)
  gemm_vg_mfma<<<dim3(9, 128), 256, 0, stream>>>(Xb, aWt, attn_b + 1024, bgv,
                                                 Vb, Ga);

  // steps 1..32 as three fused pairs; 64..512 singles; 1024 writes Y = q*v
  float* gs = Ga;
  float* gd = Gb;
  for (int nA = 1; nA <= 16; nA <<= 2) {  // nA = 1, 4, 16
    scan_pair<<<256, 1024, 0, stream>>>(gs, gd, W21t, w2t, freq_b, out_b, fid,
                                        c1, nA);
    float* t = gs; gs = gd; gd = t;
  }
  for (int n = 64; n < 1024; n <<= 1) {   // n = 64..512, 4 steps
    scan_fused<<<256, 1024, 0, stream>>>(gs, gd, W21t, w2t, freq_b, out_b, fid,
                                         c1, Vb, Xb, n, 2);
    float* t = gs; gs = gd; gd = t;
  }
  scan_fused<<<256, 1024, 0, stream>>>(gs, gd, W21t, w2t, freq_b, out_b, fid,
                                       c1, Vb, Xb, 1024, 1);

  // out = Y @ proj_W + proj_b
  gemm_proj_mfma<<<dim3(8, 128), 256, 0, stream>>>(Xb, pWt, proj_b, out);
}

// Round 15
// 356.417 us; speedup vs baseline: 1.3591x; 1.3591x over previous
//
#include <hip/hip_runtime.h>
#include <hip/hip_bf16.h>
#include <math.h>

// SSMBlock: B=8, T=2048, C=1024, NF=64. R = 16384 rows.
// Round 19: round-13 structure (best, 359.4us) + cvt_bf16 folded into
// prep_weights (blocks 0..8191 convert x -> Xb, 8192..11647 weight convs) —
// one fewer dispatch, x-conversion overlaps weight conversions.
// scan_pair dropped (5th failed scan restructure: VGPR spill at 1024thr cap).
// ws: Xb 32M | (Wqb 2M, Wob 256K) | Vb 32M | aWt+Mt 2.25M | pWt 2M
//     | w2t 256K | w1f 256K | Ga/Gb 16M | fid | c1 | bg | W21t 32K

#define R_ROWS 16384
#define T_DIM  2048
#define C_DIM  1024

typedef unsigned short u16;
typedef __attribute__((ext_vector_type(8))) short short8;
typedef __attribute__((ext_vector_type(4))) float f32x4;

__device__ __forceinline__ u16 f2bf(float f) {
  union { float f; unsigned u; } v; v.f = f;
  unsigned r = v.u + 0x7fffu + ((v.u >> 16) & 1u);
  return (u16)(r >> 16);
}
__device__ __forceinline__ float bf2f(u16 h) {
  union { unsigned u; float f; } v; v.u = ((unsigned)h) << 16;
  return v.f;
}
__device__ __forceinline__ void gld16(const void* g, void* l) {
  __builtin_amdgcn_global_load_lds(
      (const __attribute__((address_space(1))) void*)g,
      (__attribute__((address_space(3))) void*)l, 16, 0, 0);
}

// ---------------- prep megakernel 1: x conversion + weight conversions ------
// bid 0..8191      : Xb = bf16(x)   (8 f32/thread)
// bid 8192..9215   : aWt = T(attn_W v-half)
// bid 9216..10239  : pWt = T(proj_W)
// bid 10240..10367 : w2t = T(out_W)
// bid 10368..10495 : w1f from freq_W
// bid 10496..11519 : Wqb = bf16 rows of attn_W (q half)
// bid 11520..11647 : Wob = bf16 rows of out_W
__device__ __forceinline__ void cvtT_tile(const float* W, u16* Wt, int K, int N,
                                          int noff, int k0, int n0,
                                          float (*t)[33]) {
  const int tx = threadIdx.x & 31, ty = threadIdx.x >> 5;
#pragma unroll
  for (int i = 0; i < 32; i += 8)
    t[ty + i][tx] = W[(size_t)(k0 + ty + i) * N + noff + n0 + tx];
  __syncthreads();
#pragma unroll
  for (int i = 0; i < 32; i += 8)
    Wt[(size_t)(n0 + ty + i) * K + k0 + tx] = f2bf(t[tx][ty + i]);
}

__global__ __launch_bounds__(256) void prep_weights(
    const float* __restrict__ x, const float* __restrict__ attn_W,
    const float* __restrict__ proj_W, const float* __restrict__ out_W,
    const float* __restrict__ freq_W, u16* __restrict__ Xb,
    u16* __restrict__ aWt, u16* __restrict__ pWt, u16* __restrict__ w2t,
    u16* __restrict__ w1f, u16* __restrict__ Wqb, u16* __restrict__ Wob) {
  __shared__ float t[32][33];
  const int bid = blockIdx.x;
  if (bid < 8192) {
    const int i = bid * 256 + threadIdx.x;
    const float4 a = ((const float4*)x)[2 * i];
    const float4 b = ((const float4*)x)[2 * i + 1];
    alignas(16) u16 tt[8] = {f2bf(a.x), f2bf(a.y), f2bf(a.z), f2bf(a.w),
                             f2bf(b.x), f2bf(b.y), f2bf(b.z), f2bf(b.w)};
    ((uint4*)Xb)[i] = *(const uint4*)tt;
  } else if (bid < 9216) {
    const int b = bid - 8192;
    cvtT_tile(attn_W, aWt, 1024, 2048, 1024, (b & 31) * 32, (b >> 5) * 32, t);
  } else if (bid < 10240) {
    const int b = bid - 9216;
    cvtT_tile(proj_W, pWt, 1024, 1024, 0, (b & 31) * 32, (b >> 5) * 32, t);
  } else if (bid < 10368) {
    const int b = bid - 10240;
    cvtT_tile(out_W, w2t, 128, 1024, 0, (b & 3) * 32, (b >> 2) * 32, t);
  } else if (bid < 10496) {
    const int b = bid - 10368;
    const int k0 = (b & 63) * 32, n0 = (b >> 6) * 32;
    const int tx = threadIdx.x & 31, ty = threadIdx.x >> 5;
#pragma unroll
    for (int i = 0; i < 32; i += 8)
      t[ty + i][tx] = freq_W[(size_t)(k0 + ty + i) * 64 + n0 + tx];
    __syncthreads();
#pragma unroll
    for (int i = 0; i < 32; i += 8) {
      const int k = k0 + tx;
      const int row = (n0 + ty + i) + ((k >= 1024) ? 64 : 0);
      w1f[(size_t)row * 1024 + (k & 1023)] = f2bf(t[tx][ty + i]);
    }
  } else if (bid < 11520) {
    const int c = bid - 10496, k0 = threadIdx.x * 4;
    const float4 a = *(const float4*)&attn_W[(size_t)c * 2048 + k0];
    alignas(8) u16 tt[4] = {f2bf(a.x), f2bf(a.y), f2bf(a.z), f2bf(a.w)};
    *(uint2*)&Wqb[(size_t)c * 1024 + k0] = *(const uint2*)tt;
  } else {
    const int c = bid - 11520, k0 = threadIdx.x * 4;
    const float4 a = *(const float4*)&out_W[(size_t)c * 1024 + k0];
    alignas(8) u16 tt[4] = {f2bf(a.x), f2bf(a.y), f2bf(a.z), f2bf(a.w)};
    *(uint2*)&Wob[(size_t)c * 1024 + k0] = *(const uint2*)tt;
  }
}

// ---------------- prep megakernel 2: small derived tensors ------------------
__device__ __forceinline__ void gm_body(const u16* w1f, const u16* B,
                                        u16* Mt, int ldO, int n0, u16* As) {
  const int tid = threadIdx.x, lane = tid & 63, w = tid >> 6;
  const int ln = lane & 15, qd = lane >> 4;
  const int wm = w & 1, wn = w >> 1;
  const int srow = w * 32 + (lane >> 3);
  const int scol = ((lane & 7) ^ ((lane >> 3) & 7)) * 8;
  f32x4 acc[4][2] = {};
  for (int kt = 0; kt < 1024; kt += 64) {
    __syncthreads();
#pragma unroll
    for (int j = 0; j < 4; j++)
      gld16(&w1f[(size_t)(srow + j * 8) * 1024 + kt + scol],
            &As[(w * 32 + j * 8) * 64]);
    __syncthreads();
#pragma unroll
    for (int ks = 0; ks < 2; ks++) {
      short8 af[4];
#pragma unroll
      for (int i = 0; i < 4; i++) {
        const int ar = wm * 64 + i * 16 + ln;
        af[i] = *(const short8*)&As[ar * 64 + ((ks * 4 + qd) ^ (ar & 7)) * 8];
      }
#pragma unroll
      for (int nt = 0; nt < 2; nt++) {
        const short8 b = *(const short8*)&B[(size_t)(n0 + wn * 32 + nt * 16 + ln) * 1024 +
                                            kt + ks * 32 + qd * 8];
#pragma unroll
        for (int i = 0; i < 4; i++)
          acc[i][nt] = __builtin_amdgcn_mfma_f32_16x16x32_bf16(af[i], b, acc[i][nt], 0, 0, 0);
      }
    }
  }
#pragma unroll
  for (int i = 0; i < 4; i++)
#pragma unroll
    for (int nt = 0; nt < 2; nt++)
#pragma unroll
      for (int r = 0; r < 4; r++)
        Mt[(size_t)(wm * 64 + i * 16 + qd * 4 + r) * ldO +
           n0 + wn * 32 + nt * 16 + ln] = f2bf(acc[i][nt][r]);
}

__device__ __forceinline__ void dotred_body(const float* ab, const u16* w1f,
                                            float* outv, float* red) {
  const int tid = threadIdx.x, j = tid >> 1, part = tid & 1;
  float s = 0.f;
  for (int k = part * 512; k < part * 512 + 512; k++)
    s += ab[k] * bf2f(w1f[(size_t)j * 1024 + k]);
  red[tid] = s;
  __syncthreads();
  if (part == 0) outv[j] = red[2 * j] + red[2 * j + 1];
}

__global__ __launch_bounds__(256) void prep_small(
    const float* __restrict__ ident, const float* __restrict__ freq_W,
    const float* __restrict__ attn_b, const float* __restrict__ out_b,
    const u16* __restrict__ w1f, const u16* __restrict__ Wqb,
    const u16* __restrict__ Wob, float* __restrict__ fid,
    float* __restrict__ bgv, float* __restrict__ c1,
    u16* __restrict__ Mt, u16* __restrict__ W21t) {
  __shared__ u16 sh[8192];  // 16KB: gm As / reduction buffer
  float* red = (float*)sh;
  const int bid = blockIdx.x;
  if (bid == 0) {
    const int tid = threadIdx.x;
    const int j = tid >> 2, part = tid & 3;
    float s = 0.f;
    for (int k = part * 256; k < part * 256 + 256; k++)
      s += ident[k] * freq_W[(size_t)k * 64 + j];
    red[tid] = s;
    __syncthreads();
    if (part == 0) fid[j] = red[tid] + red[tid + 1] + red[tid + 2] + red[tid + 3];
  } else if (bid == 1) {
    dotred_body(attn_b, w1f, bgv, red);
  } else if (bid == 2) {
    dotred_body(out_b, w1f, c1, red);
  } else if (bid < 19) {
    gm_body(w1f, Wqb, Mt, 1024, (bid - 3) * 64, sh);
  } else {
    gm_body(w1f, Wob, W21t, 128, (bid - 19) * 64, sh);
  }
}

// ---------------- big GEMMs (m97-style + XCD swizzle) -----------------------
#define GEMM_KLOOP(Aptr, Bptr)                                                 \
  const int tid = threadIdx.x, lane = tid & 63, w = tid >> 6;                  \
  const int ln = lane & 15, qd = lane >> 4;                                    \
  const int wm = w & 1, wn = w >> 1;                                           \
  const int nbx = gridDim.x;                                                   \
  const int bid0 = blockIdx.y * nbx + blockIdx.x;                              \
  const int nwg = nbx * gridDim.y;                                             \
  const int bid = (bid0 & 7) * (nwg >> 3) + (bid0 >> 3);                       \
  const int n0 = (bid % nbx) * 128, m0 = (bid / nbx) * 128;                    \
  const int srow = w * 32 + (lane >> 3);                                       \
  const int sl = (lane & 7) ^ ((lane >> 3) & 7);                               \
  const int scol = sl * 8;                                                     \
  f32x4 acc[4][4] = {};                                                        \
  for (int kt = 0; kt < 1024; kt += 64) {                                      \
    __syncthreads();                                                           \
    _Pragma("unroll") for (int j = 0; j < 4; j++) {                            \
      gld16(&Aptr[(size_t)(m0 + srow + j * 8) * 1024 + kt + scol],             \
            &As[(w * 32 + j * 8) * 64]);                                       \
      gld16(&Bptr[(size_t)(n0 + srow + j * 8) * 1024 + kt + scol],             \
            &Bs[(w * 32 + j * 8) * 64]);                                       \
    }                                                                          \
    __syncthreads();                                                           \
    _Pragma("unroll") for (int ks = 0; ks < 2; ks++) {                         \
      short8 af[4], bf_[4];                                                    \
      _Pragma("unroll") for (int i = 0; i < 4; i++) {                          \
        const int ar = wm * 64 + i * 16 + ln;                                  \
        af[i] = *(const short8*)&As[ar * 64 + ((ks * 4 + qd) ^ (ar & 7)) * 8]; \
      }                                                                        \
      _Pragma("unroll") for (int j = 0; j < 4; j++) {                          \
        const int br = wn * 64 + j * 16 + ln;                                  \
        bf_[j] = *(const short8*)&Bs[br * 64 + ((ks * 4 + qd) ^ (br & 7)) * 8];\
      }                                                                        \
      _Pragma("unroll") for (int i = 0; i < 4; i++)                            \
      _Pragma("unroll") for (int j = 0; j < 4; j++)                            \
        acc[i][j] = __builtin_amdgcn_mfma_f32_16x16x32_bf16(af[i], bf_[j],     \
                                                            acc[i][j], 0, 0, 0);\
    }                                                                          \
  }                                                                            \
  __syncthreads();

// V = x @ attn_Wv + b_v (n0 < 1024)  |  G0 = x @ Mt^T + bg (n0 == 1024).
__global__ __launch_bounds__(256) void gemm_vg_mfma(
    const u16* __restrict__ A, const u16* __restrict__ Bt,
    const float* __restrict__ bias, const float* __restrict__ bg,
    u16* __restrict__ Vb, float* __restrict__ G) {
  __shared__ u16 S[16384];
  u16* As = S;
  u16* Bs = S + 8192;
  GEMM_KLOOP(A, Bt)
  if (n0 < 1024) {
#pragma unroll
    for (int j = 0; j < 4; j++) {
      const int col = wn * 64 + j * 16 + ln;
      const float bv = bias[n0 + col];
#pragma unroll
      for (int i = 0; i < 4; i++)
#pragma unroll
        for (int r = 0; r < 4; r++)
          S[(wm * 64 + i * 16 + qd * 4 + r) * 128 + col] = f2bf(acc[i][j][r] + bv);
    }
    __syncthreads();
#pragma unroll
    for (int it = 0; it < 8; it++) {
      const int idx = it * 256 + tid;
      const int row = idx >> 4, seg = idx & 15;
      *(uint4*)&Vb[(size_t)(m0 + row) * 1024 + n0 + seg * 8] = ((const uint4*)S)[idx];
    }
  } else {  // G0 block: direct f32 write, bias bg
#pragma unroll
    for (int j = 0; j < 4; j++) {
      const int col = wn * 64 + j * 16 + ln;
      const float bv = bg[col];
#pragma unroll
      for (int i = 0; i < 4; i++)
#pragma unroll
        for (int r = 0; r < 4; r++)
          G[(size_t)(m0 + wm * 64 + i * 16 + qd * 4 + r) * 128 + col] =
              acc[i][j][r] + bv;
    }
  }
}

__global__ __launch_bounds__(256) void gemm_proj_mfma(
    const u16* __restrict__ A, const u16* __restrict__ Bt,
    const float* __restrict__ bias, float* __restrict__ OUT) {
  __shared__ u16 S[16384];
  u16* As = S;
  u16* Bs = S + 8192;
  GEMM_KLOOP(A, Bt)
  float* Csf = (float*)S;
#pragma unroll
  for (int p = 0; p < 2; p++) {
    if (wm == p) {
#pragma unroll
      for (int j = 0; j < 4; j++) {
        const int col = wn * 64 + j * 16 + ln;
        const float bv = bias[n0 + col];
#pragma unroll
        for (int i = 0; i < 4; i++)
#pragma unroll
          for (int r = 0; r < 4; r++)
            Csf[(i * 16 + qd * 4 + r) * 128 + col] = acc[i][j][r] + bv;
      }
    }
    __syncthreads();
#pragma unroll
    for (int it = 0; it < 8; it++) {
      const int idx = it * 256 + tid;
      const int row = idx >> 5, seg = idx & 31;
      *(uint4*)&OUT[(size_t)(m0 + p * 64 + row) * 1024 + n0 + seg * 4] =
          ((const uint4*)Csf)[idx];
    }
    __syncthreads();
  }
}

// ---------------- fused scan step (round-13 body + XCD row map) --------------
// 1024 threads (16 waves), 64 rows/block, grid 256.
// r0 map: XCD k owns contiguous rows [k*2048,(k+1)*2048) (= one sequence),
// so all shifted reads stay in the writer XCD's L2.
// flags: 1 = last step: write Y = q*v into Yout ; 2 = compute Gdst.
__global__ __launch_bounds__(1024, 4) void scan_fused(
    const float* __restrict__ Gsrc, float* __restrict__ Gdst,
    const u16* __restrict__ W21t, const u16* __restrict__ W2t,
    const float* __restrict__ b1, const float* __restrict__ b2,
    const float* __restrict__ fid, const float* __restrict__ c1,
    const u16* __restrict__ Vb, u16* __restrict__ Yout, int n, int flags) {
  __shared__ u16 S[64 * 128];  // 16KB
  __shared__ unsigned rmax[64];
  const int tid = threadIdx.x, lane = tid & 63, wv = tid >> 6;
  const int ln = lane & 15, qd = lane >> 4;
  const int bid = blockIdx.x;
  const int r0 = (((bid & 7) << 5) + (bid >> 3)) * 64;
  if (tid < 64) rmax[tid] = 0u;
  // ---- P0
  {
    const int r = tid >> 4, js = (tid & 15) << 2;
    const int gr = r0 + r, tl = gr & (T_DIM - 1);
    const float* g1p = (tl >= n) ? &Gsrc[(size_t)(gr - n) * 128 + js] : &fid[js];
    const float4 g1 = *(const float4*)g1p;
    const float4 g2 = *(const float4*)&Gsrc[(size_t)gr * 128 + 64 + js];
    const float4 bb = *(const float4*)&b1[js];
    float f[4] = {g1.x + g2.x + bb.x, g1.y + g2.y + bb.y,
                  g1.z + g2.z + bb.z, g1.w + g2.w + bb.w};
    alignas(8) u16 sn[4], cs[4];
#pragma unroll
    for (int c = 0; c < 4; c++) {
      float sv, cv;
      __sincosf(f[c], &sv, &cv);
      sn[c] = f2bf(sv);
      cs[c] = f2bf(cv);
    }
    const int u = js >> 3, half = (js >> 2) & 1, rx = r & 7;
    const int ps = (u ^ rx) & 7;
    const int pc = 8 | ps;
    *(uint2*)&S[r * 128 + ps * 8 + half * 4] = *(const uint2*)sn;
    *(uint2*)&S[r * 128 + pc * 8 + half * 4] = *(const uint2*)cs;
  }
  __syncthreads();
  // ---- P1: z2^T; wave owns 64 cols
  const u16* w2b = W2t + (size_t)wv * 64 * 128;
  f32x4 acc[4][4] = {};
#pragma unroll
  for (int ks = 0; ks < 4; ks++) {
    short8 af[4];
#pragma unroll
    for (int i = 0; i < 4; i++) {
      const int ar = i * 16 + ln;
      const int u = ks * 4 + qd;
      af[i] = *(const short8*)&S[ar * 128 + ((u & 8) | ((u ^ ar) & 7)) * 8];
    }
#pragma unroll
    for (int nt = 0; nt < 4; nt++) {
      const short8 b = *(const short8*)&w2b[(size_t)(nt * 16 + ln) * 128 + ks * 32 + qd * 8];
#pragma unroll
      for (int i = 0; i < 4; i++)
        acc[i][nt] = __builtin_amdgcn_mfma_f32_16x16x32_bf16(b, af[i], acc[i][nt], 0, 0, 0);
    }
  }
  float mx[4] = {0.f, 0.f, 0.f, 0.f};
#pragma unroll
  for (int nt = 0; nt < 4; nt++) {
    const float4 bb = *(const float4*)&b2[wv * 64 + nt * 16 + qd * 4];
    const float br4[4] = {bb.x, bb.y, bb.z, bb.w};
#pragma unroll
    for (int i = 0; i < 4; i++)
#pragma unroll
      for (int r = 0; r < 4; r++) {
        const float v = acc[i][nt][r] + br4[r];
        acc[i][nt][r] = v;
        mx[i] = fmaxf(mx[i], fabsf(v));
      }
  }
#pragma unroll
  for (int i = 0; i < 4; i++) {
    float v = mx[i];
    v = fmaxf(v, __shfl_xor(v, 16, 64));
    v = fmaxf(v, __shfl_xor(v, 32, 64));
    if (lane < 16) atomicMax(&rmax[i * 16 + lane], __float_as_uint(v));
  }
  __syncthreads();
  if (flags & 1) {  // last step: Y = (z2*inv) * v
    float inv[4];
#pragma unroll
    for (int i = 0; i < 4; i++)
      inv[i] = 1.0f / (__uint_as_float(rmax[i * 16 + ln]) + 1e-6f);
#pragma unroll
    for (int i = 0; i < 4; i++) {
      const int row = i * 16 + ln;
#pragma unroll
      for (int nt = 0; nt < 4; nt++) {
        const int col = wv * 64 + nt * 16 + qd * 4;
        const uint2 vv = *(const uint2*)&Vb[(size_t)(r0 + row) * 1024 + col];
        const u16* vp = (const u16*)&vv;
        uint2 pv;
        pv.x = (unsigned)f2bf(acc[i][nt][0] * inv[i] * bf2f(vp[0])) |
               ((unsigned)f2bf(acc[i][nt][1] * inv[i] * bf2f(vp[1])) << 16);
        pv.y = (unsigned)f2bf(acc[i][nt][2] * inv[i] * bf2f(vp[2])) |
               ((unsigned)f2bf(acc[i][nt][3] * inv[i] * bf2f(vp[3])) << 16);
        *(uint2*)&Yout[(size_t)(r0 + row) * 1024 + col] = pv;
      }
    }
  }
  if (flags & 2) {  // G' = (S @ W21t^T + c1) * inv : 64x128 out, K=128
    const int wm3 = wv & 3, wn3 = wv >> 2;
    f32x4 g[2] = {};
#pragma unroll
    for (int ks = 0; ks < 4; ks++) {
      const int ar = wm3 * 16 + ln;
      const int u = ks * 4 + qd;
      const short8 a = *(const short8*)&S[ar * 128 + ((u & 8) | ((u ^ ar) & 7)) * 8];
#pragma unroll
      for (int c = 0; c < 2; c++) {
        const short8 b = *(const short8*)&W21t[(size_t)(wn3 * 32 + c * 16 + ln) * 128 +
                                               ks * 32 + qd * 8];
        g[c] = __builtin_amdgcn_mfma_f32_16x16x32_bf16(a, b, g[c], 0, 0, 0);
      }
    }
#pragma unroll
    for (int c = 0; c < 2; c++) {
      const int col = wn3 * 32 + c * 16 + ln;
      const float cb = c1[col];
#pragma unroll
      for (int r = 0; r < 4; r++) {
        const int row = wm3 * 16 + qd * 4 + r;
        const float invr = 1.0f / (__uint_as_float(rmax[row]) + 1e-6f);
        Gdst[(size_t)(r0 + row) * 128 + col] = (g[c][r] + cb) * invr;
      }
    }
  }
}

// ---------------- launch ----------------------------------------------------
extern "C" void kernel_launch(void* const* d_in, const int* in_sizes, int n_in,
                              void* d_out, int out_size, void* d_ws, size_t ws_size,
                              hipStream_t stream) {
  const float* x      = (const float*)d_in[0];
  const float* attn_W = (const float*)d_in[1];
  const float* attn_b = (const float*)d_in[2];
  const float* freq_W = (const float*)d_in[3];
  const float* freq_b = (const float*)d_in[4];
  const float* out_W  = (const float*)d_in[5];
  const float* out_b  = (const float*)d_in[6];
  const float* proj_W = (const float*)d_in[7];
  const float* proj_b = (const float*)d_in[8];
  const float* ident  = (const float*)d_in[9];
  float* out = (float*)d_out;

  const size_t RC = (size_t)R_ROWS * C_DIM;
  u16* Xb  = (u16*)d_ws;                     // 32MB (x bf16, later Y)
  u16* Qb  = Xb + RC;                        // 32MB region, repurposed:
  u16* Wqb = Qb;                             //   attn_Wq bf16 [1024][1024] 2MB
  u16* Wob = Qb + (size_t)1024 * 1024;       //   out_W bf16 [128][1024] 256KB
  u16* Vb  = Qb + RC;                        // 32MB
  u16* aWt = Vb + RC;                        // B = [aWt 1024 rows | Mt 128 rows]
  u16* Mt  = aWt + (size_t)1024 * 1024;      //   (2.25MB of the 4MB region)
  u16* pWt = aWt + (size_t)2048 * 1024;      // 2MB
  u16* w2t = pWt + (size_t)1024 * 1024;      // 256KB
  u16* w1f = w2t + (size_t)1024 * 128;       // 256KB
  float* Ga  = (float*)(w1f + (size_t)128 * 1024);  // 8MB
  float* Gb  = Ga + (size_t)R_ROWS * 128;           // 8MB
  float* fid = Gb + (size_t)R_ROWS * 128;           // 256B
  float* c1  = fid + 64;                            // 512B
  float* bgv = c1 + 128;                            // 512B
  u16* W21t  = (u16*)(bgv + 128);                   // 32KB

  // prep (2 dispatches)
  prep_weights<<<11648, 256, 0, stream>>>(x, attn_W, proj_W, out_W, freq_W,
                                          Xb, aWt, pWt, w2t, w1f, Wqb, Wob);
  prep_small<<<21, 256, 0, stream>>>(ident, freq_W, attn_b, out_b, w1f, Wqb,
                                     Wob, fid, bgv, c1, Mt, W21t);

  // V = x @ attn_Wv + b_v  AND  G0 = x @ Mt^T + bg (fused, grid 9x128)
  gemm_vg_mfma<<<dim3(9, 128), 256, 0, stream>>>(Xb, aWt, attn_b + 1024, bgv,
                                                 Vb, Ga);

  // 11 scan steps (64 rows/block, grid 256); last writes Y = q*v into Xb
  float* gs = Ga;
  float* gd = Gb;
  for (int n = 1; n < 1024; n <<= 1) {   // n = 1..512, 10 steps
    scan_fused<<<256, 1024, 0, stream>>>(gs, gd, W21t, w2t, freq_b, out_b, fid,
                                         c1, Vb, Xb, n, 2);
    float* t = gs; gs = gd; gd = t;
  }
  scan_fused<<<256, 1024, 0, stream>>>(gs, gd, W21t, w2t, freq_b, out_b, fid,
                                       c1, Vb, Xb, 1024, 1);

  // out = Y @ proj_W + proj_b
  gemm_proj_mfma<<<dim3(8, 128), 256, 0, stream>>>(Xb, pWt, proj_b, out);
}